// Round 1
// baseline (904.783 us; speedup 1.0000x reference)
//
#include <hip/hip_runtime.h>
#include <hip/hip_bf16.h>

#define NLEV 16
#define TSIZE (1u << 19)
#define TMASK ((1u << 19) - 1u)
#define P1 2654435761u
#define P2 805459861u

// floor(16 * b^l), b = 256^(1/15) — matches numpy float64 computation.
__device__ __constant__ float c_res[NLEV] = {
    16.f, 23.f, 33.f, 48.f, 70.f, 101.f, 147.f, 212.f,
    307.f, 445.f, 645.f, 933.f, 1351.f, 1955.f, 2830.f, 4096.f};

__global__ __launch_bounds__(256) void hashgrid_radiance_kernel(
    const float* __restrict__ pos,     // [N,3]
    const float* __restrict__ table,   // [16, 2^19, 2]
    const float* __restrict__ W0,      // [32,64]
    const float* __restrict__ W1,      // [64,64]
    const float* __restrict__ W2,      // [64,64]
    const float* __restrict__ W3,      // [64,4]
    float* __restrict__ out,           // rgb [N,3] then density [N]
    int n)
{
    int id = blockIdx.x * 256 + threadIdx.x;
    int i = id < n ? id : n - 1;   // no early return: keep weight loads in uniform CF

    float p0 = pos[3 * i + 0];
    float p1 = pos[3 * i + 1];
    float p2 = pos[3 * i + 2];
    float x = (p0 + 1.f) * 0.5f;
    float y = (p1 + 1.f) * 0.5f;
    float z = (p2 + 1.f) * 0.5f;
    bool sel = (x > 0.f) && (x < 1.f) && (y > 0.f) && (y < 1.f) &&
               (z > 0.f) && (z < 1.f);

    // ---- hash encode + layer 0 (interleaved; h0[j] static-indexed) ----
    float h0[64];
#pragma unroll
    for (int j = 0; j < 64; ++j) h0[j] = 0.f;

    const float2* tb = (const float2*)table;
#pragma unroll
    for (int l = 0; l < NLEV; ++l) {
        float r = c_res[l];
        float sx = x * r, sy = y * r, sz = z * r;
        float fx = floorf(sx), fy = floorf(sy), fz = floorf(sz);
        float wx = sx - fx, wy = sy - fy, wz = sz - fz;
        unsigned ix = (unsigned)fx, iy = (unsigned)fy, iz = (unsigned)fz;
        unsigned hy0 = iy * P1, hy1 = hy0 + P1;
        unsigned hz0 = iz * P2, hz1 = hz0 + P2;
        unsigned a00 = hy0 ^ hz0, a10 = hy1 ^ hz0;
        unsigned a01 = hy0 ^ hz1, a11 = hy1 ^ hz1;
        unsigned ix1 = ix + 1u;
        const float2* tl = tb + (size_t)l * TSIZE;
        // issue all 8 gathers, then blend
        float2 e000 = tl[(ix  ^ a00) & TMASK];
        float2 e100 = tl[(ix1 ^ a00) & TMASK];
        float2 e010 = tl[(ix  ^ a10) & TMASK];
        float2 e110 = tl[(ix1 ^ a10) & TMASK];
        float2 e001 = tl[(ix  ^ a01) & TMASK];
        float2 e101 = tl[(ix1 ^ a01) & TMASK];
        float2 e011 = tl[(ix  ^ a11) & TMASK];
        float2 e111 = tl[(ix1 ^ a11) & TMASK];

        float ux = 1.f - wx, uy = 1.f - wy, uz = 1.f - wz;
        float w000 = ux * uy * uz, w100 = wx * uy * uz;
        float w010 = ux * wy * uz, w110 = wx * wy * uz;
        float w001 = ux * uy * wz, w101 = wx * uy * wz;
        float w011 = ux * wy * wz, w111 = wx * wy * wz;

        float f0 = e000.x * w000 + e100.x * w100 + e010.x * w010 + e110.x * w110 +
                   e001.x * w001 + e101.x * w101 + e011.x * w011 + e111.x * w111;
        float f1 = e000.y * w000 + e100.y * w100 + e010.y * w010 + e110.y * w110 +
                   e001.y * w001 + e101.y * w101 + e011.y * w011 + e111.y * w111;

        const float* w0a = W0 + (2 * l) * 64;
        const float* w0b = W0 + (2 * l + 1) * 64;
#pragma unroll
        for (int j = 0; j < 64; ++j)
            h0[j] = fmaf(f0, w0a[j], fmaf(f1, w0b[j], h0[j]));
    }
#pragma unroll
    for (int j = 0; j < 64; ++j) h0[j] = fmaxf(h0[j], 0.f);

    // ---- layer 1: h1 = relu(h0 @ W1) ----
    float h1[64];
#pragma unroll
    for (int j = 0; j < 64; ++j) h1[j] = 0.f;
#pragma unroll
    for (int k = 0; k < 64; ++k) {
        float v = h0[k];
        const float* wr = W1 + k * 64;
#pragma unroll
        for (int j = 0; j < 64; ++j) h1[j] = fmaf(v, wr[j], h1[j]);
    }
#pragma unroll
    for (int j = 0; j < 64; ++j) h1[j] = fmaxf(h1[j], 0.f);

    // ---- layer 2: h2 = relu(h1 @ W2)  (reuse h0 storage) ----
#pragma unroll
    for (int j = 0; j < 64; ++j) h0[j] = 0.f;
#pragma unroll
    for (int k = 0; k < 64; ++k) {
        float v = h1[k];
        const float* wr = W2 + k * 64;
#pragma unroll
        for (int j = 0; j < 64; ++j) h0[j] = fmaf(v, wr[j], h0[j]);
    }
#pragma unroll
    for (int j = 0; j < 64; ++j) h0[j] = fmaxf(h0[j], 0.f);

    // ---- layer 3: out4 = h2 @ W3 ----
    float o0 = 0.f, o1 = 0.f, o2 = 0.f, o3 = 0.f;
#pragma unroll
    for (int k = 0; k < 64; ++k) {
        float v = h0[k];
        const float* wr = W3 + k * 4;
        o0 = fmaf(v, wr[0], o0);
        o1 = fmaf(v, wr[1], o1);
        o2 = fmaf(v, wr[2], o2);
        o3 = fmaf(v, wr[3], o3);
    }

    if (id < n) {
        float r = 1.f / (1.f + expf(-o0));
        float g = 1.f / (1.f + expf(-o1));
        float b = 1.f / (1.f + expf(-o2));
        float d = expf(o3 - 1.f) * (sel ? 1.f : 0.f);
        out[3 * (size_t)i + 0] = r;
        out[3 * (size_t)i + 1] = g;
        out[3 * (size_t)i + 2] = b;
        out[3 * (size_t)n + i] = d;
    }
}

extern "C" void kernel_launch(void* const* d_in, const int* in_sizes, int n_in,
                              void* d_out, int out_size, void* d_ws, size_t ws_size,
                              hipStream_t stream) {
    const float* pos   = (const float*)d_in[0];
    const float* table = (const float*)d_in[1];
    const float* W0    = (const float*)d_in[2];
    const float* W1    = (const float*)d_in[3];
    const float* W2    = (const float*)d_in[4];
    const float* W3    = (const float*)d_in[5];
    float* out = (float*)d_out;
    int n = in_sizes[0] / 3;
    int grid = (n + 255) / 256;
    hipLaunchKernelGGL(hashgrid_radiance_kernel, dim3(grid), dim3(256), 0, stream,
                       pos, table, W0, W1, W2, W3, out, n);
}

// Round 2
// 389.310 us; speedup vs baseline: 2.3241x; 2.3241x over previous
//
#include <hip/hip_runtime.h>
#include <hip/hip_bf16.h>

#define NLEV 16
#define TSIZE (1u << 19)
#define TMASK ((1u << 19) - 1u)
#define P1 2654435761u
#define P2 805459861u

// floor(16 * b^l), b = 256^(1/15) — matches numpy float64 computation.
__device__ __constant__ float c_res[NLEV] = {
    16.f, 23.f, 33.f, 48.f, 70.f, 101.f, 147.f, 212.f,
    307.f, 445.f, 645.f, 933.f, 1351.f, 1955.f, 2830.f, 4096.f};

// ---------------- Phase 1: hash encode, thread per (point, level) ----------
__global__ __launch_bounds__(256) void hash_encode_kernel(
    const float* __restrict__ pos,     // [N,3]
    const float* __restrict__ table,   // [16, 2^19, 2]
    __hip_bfloat162* __restrict__ feat, // [16][N] level-major
    int n)
{
    int i = blockIdx.x * 256 + threadIdx.x;
    int l = blockIdx.y;
    if (i >= n) return;

    float x = (pos[3 * i + 0] + 1.f) * 0.5f;
    float y = (pos[3 * i + 1] + 1.f) * 0.5f;
    float z = (pos[3 * i + 2] + 1.f) * 0.5f;

    float r = c_res[l];
    float sx = x * r, sy = y * r, sz = z * r;
    float fx = floorf(sx), fy = floorf(sy), fz = floorf(sz);
    float wx = sx - fx, wy = sy - fy, wz = sz - fz;
    unsigned ix = (unsigned)fx, iy = (unsigned)fy, iz = (unsigned)fz;
    unsigned hy0 = iy * P1, hy1 = hy0 + P1;
    unsigned hz0 = iz * P2, hz1 = hz0 + P2;
    unsigned a00 = hy0 ^ hz0, a10 = hy1 ^ hz0;
    unsigned a01 = hy0 ^ hz1, a11 = hy1 ^ hz1;
    unsigned ix1 = ix + 1u;

    const float2* tl = (const float2*)table + (size_t)l * TSIZE;
    // 8 independent gathers, all issued before any use
    float2 e000 = tl[(ix  ^ a00) & TMASK];
    float2 e100 = tl[(ix1 ^ a00) & TMASK];
    float2 e010 = tl[(ix  ^ a10) & TMASK];
    float2 e110 = tl[(ix1 ^ a10) & TMASK];
    float2 e001 = tl[(ix  ^ a01) & TMASK];
    float2 e101 = tl[(ix1 ^ a01) & TMASK];
    float2 e011 = tl[(ix  ^ a11) & TMASK];
    float2 e111 = tl[(ix1 ^ a11) & TMASK];

    float ux = 1.f - wx, uy = 1.f - wy, uz = 1.f - wz;
    float w000 = ux * uy * uz, w100 = wx * uy * uz;
    float w010 = ux * wy * uz, w110 = wx * wy * uz;
    float w001 = ux * uy * wz, w101 = wx * uy * wz;
    float w011 = ux * wy * wz, w111 = wx * wy * wz;

    float f0 = e000.x * w000 + e100.x * w100 + e010.x * w010 + e110.x * w110 +
               e001.x * w001 + e101.x * w101 + e011.x * w011 + e111.x * w111;
    float f1 = e000.y * w000 + e100.y * w100 + e010.y * w010 + e110.y * w110 +
               e001.y * w001 + e101.y * w101 + e011.y * w011 + e111.y * w111;

    __hip_bfloat162 v;
    v.x = __float2bfloat16(f0);
    v.y = __float2bfloat16(f1);
    feat[(size_t)l * n + i] = v;
}

// ---------------- Phase 2: scalar fp32 MLP, thread per point ---------------
__global__ __launch_bounds__(256) void mlp_kernel(
    const float* __restrict__ pos,
    const __hip_bfloat162* __restrict__ feat,  // [16][N]
    const float* __restrict__ W0,      // [32,64]
    const float* __restrict__ W1,      // [64,64]
    const float* __restrict__ W2,      // [64,64]
    const float* __restrict__ W3,      // [64,4]
    float* __restrict__ out,           // rgb [N,3] then density [N]
    int n)
{
    int id = blockIdx.x * 256 + threadIdx.x;
    int i = id < n ? id : n - 1;   // no early return: keep weight loads uniform

    float x = (pos[3 * i + 0] + 1.f) * 0.5f;
    float y = (pos[3 * i + 1] + 1.f) * 0.5f;
    float z = (pos[3 * i + 2] + 1.f) * 0.5f;
    bool sel = (x > 0.f) && (x < 1.f) && (y > 0.f) && (y < 1.f) &&
               (z > 0.f) && (z < 1.f);

    float h0[64];
#pragma unroll
    for (int j = 0; j < 64; ++j) h0[j] = 0.f;

#pragma unroll
    for (int l = 0; l < NLEV; ++l) {
        __hip_bfloat162 v = feat[(size_t)l * n + i];
        float f0 = __bfloat162float(v.x);
        float f1 = __bfloat162float(v.y);
        const float* w0a = W0 + (2 * l) * 64;
        const float* w0b = W0 + (2 * l + 1) * 64;
#pragma unroll
        for (int j = 0; j < 64; ++j)
            h0[j] = fmaf(f0, w0a[j], fmaf(f1, w0b[j], h0[j]));
    }
#pragma unroll
    for (int j = 0; j < 64; ++j) h0[j] = fmaxf(h0[j], 0.f);

    float h1[64];
#pragma unroll
    for (int j = 0; j < 64; ++j) h1[j] = 0.f;
#pragma unroll
    for (int k = 0; k < 64; ++k) {
        float v = h0[k];
        const float* wr = W1 + k * 64;
#pragma unroll
        for (int j = 0; j < 64; ++j) h1[j] = fmaf(v, wr[j], h1[j]);
    }
#pragma unroll
    for (int j = 0; j < 64; ++j) h1[j] = fmaxf(h1[j], 0.f);

#pragma unroll
    for (int j = 0; j < 64; ++j) h0[j] = 0.f;
#pragma unroll
    for (int k = 0; k < 64; ++k) {
        float v = h1[k];
        const float* wr = W2 + k * 64;
#pragma unroll
        for (int j = 0; j < 64; ++j) h0[j] = fmaf(v, wr[j], h0[j]);
    }
#pragma unroll
    for (int j = 0; j < 64; ++j) h0[j] = fmaxf(h0[j], 0.f);

    float o0 = 0.f, o1 = 0.f, o2 = 0.f, o3 = 0.f;
#pragma unroll
    for (int k = 0; k < 64; ++k) {
        float v = h0[k];
        const float* wr = W3 + k * 4;
        o0 = fmaf(v, wr[0], o0);
        o1 = fmaf(v, wr[1], o1);
        o2 = fmaf(v, wr[2], o2);
        o3 = fmaf(v, wr[3], o3);
    }

    if (id < n) {
        float r = 1.f / (1.f + expf(-o0));
        float g = 1.f / (1.f + expf(-o1));
        float b = 1.f / (1.f + expf(-o2));
        float d = expf(o3 - 1.f) * (sel ? 1.f : 0.f);
        out[3 * (size_t)i + 0] = r;
        out[3 * (size_t)i + 1] = g;
        out[3 * (size_t)i + 2] = b;
        out[3 * (size_t)n + i] = d;
    }
}

// ---------------- Fallback: round-1 fused kernel (if ws too small) ---------
__global__ __launch_bounds__(256) void hashgrid_fused_kernel(
    const float* __restrict__ pos, const float* __restrict__ table,
    const float* __restrict__ W0, const float* __restrict__ W1,
    const float* __restrict__ W2, const float* __restrict__ W3,
    float* __restrict__ out, int n)
{
    int id = blockIdx.x * 256 + threadIdx.x;
    int i = id < n ? id : n - 1;

    float x = (pos[3 * i + 0] + 1.f) * 0.5f;
    float y = (pos[3 * i + 1] + 1.f) * 0.5f;
    float z = (pos[3 * i + 2] + 1.f) * 0.5f;
    bool sel = (x > 0.f) && (x < 1.f) && (y > 0.f) && (y < 1.f) &&
               (z > 0.f) && (z < 1.f);

    float h0[64];
#pragma unroll
    for (int j = 0; j < 64; ++j) h0[j] = 0.f;

    const float2* tb = (const float2*)table;
#pragma unroll
    for (int l = 0; l < NLEV; ++l) {
        float r = c_res[l];
        float sx = x * r, sy = y * r, sz = z * r;
        float fx = floorf(sx), fy = floorf(sy), fz = floorf(sz);
        float wx = sx - fx, wy = sy - fy, wz = sz - fz;
        unsigned ix = (unsigned)fx, iy = (unsigned)fy, iz = (unsigned)fz;
        unsigned hy0 = iy * P1, hy1 = hy0 + P1;
        unsigned hz0 = iz * P2, hz1 = hz0 + P2;
        unsigned a00 = hy0 ^ hz0, a10 = hy1 ^ hz0;
        unsigned a01 = hy0 ^ hz1, a11 = hy1 ^ hz1;
        unsigned ix1 = ix + 1u;
        const float2* tl = tb + (size_t)l * TSIZE;
        float2 e000 = tl[(ix  ^ a00) & TMASK];
        float2 e100 = tl[(ix1 ^ a00) & TMASK];
        float2 e010 = tl[(ix  ^ a10) & TMASK];
        float2 e110 = tl[(ix1 ^ a10) & TMASK];
        float2 e001 = tl[(ix  ^ a01) & TMASK];
        float2 e101 = tl[(ix1 ^ a01) & TMASK];
        float2 e011 = tl[(ix  ^ a11) & TMASK];
        float2 e111 = tl[(ix1 ^ a11) & TMASK];

        float ux = 1.f - wx, uy = 1.f - wy, uz = 1.f - wz;
        float w000 = ux * uy * uz, w100 = wx * uy * uz;
        float w010 = ux * wy * uz, w110 = wx * wy * uz;
        float w001 = ux * uy * wz, w101 = wx * uy * wz;
        float w011 = ux * wy * wz, w111 = wx * wy * wz;

        float f0 = e000.x * w000 + e100.x * w100 + e010.x * w010 + e110.x * w110 +
                   e001.x * w001 + e101.x * w101 + e011.x * w011 + e111.x * w111;
        float f1 = e000.y * w000 + e100.y * w100 + e010.y * w010 + e110.y * w110 +
                   e001.y * w001 + e101.y * w101 + e011.y * w011 + e111.y * w111;

        const float* w0a = W0 + (2 * l) * 64;
        const float* w0b = W0 + (2 * l + 1) * 64;
#pragma unroll
        for (int j = 0; j < 64; ++j)
            h0[j] = fmaf(f0, w0a[j], fmaf(f1, w0b[j], h0[j]));
    }
#pragma unroll
    for (int j = 0; j < 64; ++j) h0[j] = fmaxf(h0[j], 0.f);

    float h1[64];
#pragma unroll
    for (int j = 0; j < 64; ++j) h1[j] = 0.f;
#pragma unroll
    for (int k = 0; k < 64; ++k) {
        float v = h0[k];
        const float* wr = W1 + k * 64;
#pragma unroll
        for (int j = 0; j < 64; ++j) h1[j] = fmaf(v, wr[j], h1[j]);
    }
#pragma unroll
    for (int j = 0; j < 64; ++j) h1[j] = fmaxf(h1[j], 0.f);

#pragma unroll
    for (int j = 0; j < 64; ++j) h0[j] = 0.f;
#pragma unroll
    for (int k = 0; k < 64; ++k) {
        float v = h1[k];
        const float* wr = W2 + k * 64;
#pragma unroll
        for (int j = 0; j < 64; ++j) h0[j] = fmaf(v, wr[j], h0[j]);
    }
#pragma unroll
    for (int j = 0; j < 64; ++j) h0[j] = fmaxf(h0[j], 0.f);

    float o0 = 0.f, o1 = 0.f, o2 = 0.f, o3 = 0.f;
#pragma unroll
    for (int k = 0; k < 64; ++k) {
        float v = h0[k];
        const float* wr = W3 + k * 4;
        o0 = fmaf(v, wr[0], o0);
        o1 = fmaf(v, wr[1], o1);
        o2 = fmaf(v, wr[2], o2);
        o3 = fmaf(v, wr[3], o3);
    }

    if (id < n) {
        float r = 1.f / (1.f + expf(-o0));
        float g = 1.f / (1.f + expf(-o1));
        float b = 1.f / (1.f + expf(-o2));
        float d = expf(o3 - 1.f) * (sel ? 1.f : 0.f);
        out[3 * (size_t)i + 0] = r;
        out[3 * (size_t)i + 1] = g;
        out[3 * (size_t)i + 2] = b;
        out[3 * (size_t)n + i] = d;
    }
}

extern "C" void kernel_launch(void* const* d_in, const int* in_sizes, int n_in,
                              void* d_out, int out_size, void* d_ws, size_t ws_size,
                              hipStream_t stream) {
    const float* pos   = (const float*)d_in[0];
    const float* table = (const float*)d_in[1];
    const float* W0    = (const float*)d_in[2];
    const float* W1    = (const float*)d_in[3];
    const float* W2    = (const float*)d_in[4];
    const float* W3    = (const float*)d_in[5];
    float* out = (float*)d_out;
    int n = in_sizes[0] / 3;
    int grid = (n + 255) / 256;

    size_t feat_bytes = (size_t)NLEV * n * sizeof(__hip_bfloat162);
    if (ws_size >= feat_bytes) {
        __hip_bfloat162* feat = (__hip_bfloat162*)d_ws;
        hipLaunchKernelGGL(hash_encode_kernel, dim3(grid, NLEV), dim3(256), 0, stream,
                           pos, table, feat, n);
        hipLaunchKernelGGL(mlp_kernel, dim3(grid), dim3(256), 0, stream,
                           pos, feat, W0, W1, W2, W3, out, n);
    } else {
        hipLaunchKernelGGL(hashgrid_fused_kernel, dim3(grid), dim3(256), 0, stream,
                           pos, table, W0, W1, W2, W3, out, n);
    }
}